// Round 7
// baseline (2618.857 us; speedup 1.0000x reference)
//
#include <hip/hip_runtime.h>
#include <hip/hip_bf16.h>

#define SEQ  2048
#define BAT  64
#define HID  128
#define LDSP 136   // padded LDS row: 272 B

// workspace layout
#define XB_OFF  (1u << 20)            // bf16 x, 32 MiB
#define IL_OFF  (35u << 20)           // f32 ilogm1[t][b], 512 KiB
#define XG_OFF  ((size_t)36 << 20)    // f32 xg[d][t][b][4 gates] per dim j (float4), 512 MiB
#define WS_NEED ((size_t)(36 + 512 + 1) << 20)   // +1 MiB guard for prefetch overrun

typedef __bf16 bf16x8 __attribute__((ext_vector_type(8)));
typedef float  f32x4  __attribute__((ext_vector_type(4)));

#define MFMA(a,b,c) __builtin_amdgcn_mfma_f32_16x16x32_bf16((a),(b),(c),0,0,0)

__device__ __forceinline__ float sig_f(float x) {
    return __fdividef(1.0f, 1.0f + __expf(-x));
}
__device__ __forceinline__ float tanh_f(float x) {
    return 1.0f - __fdividef(2.0f, 1.0f + __expf(2.0f * x));
}
__device__ __forceinline__ bf16x8 cvt8(const float* p) {
    bf16x8 r;
    #pragma unroll
    for (int i = 0; i < 8; ++i) r[i] = (__bf16)p[i];
    return r;
}

// ---- pre-kernel 1: x f32 -> bf16, same [S][B][I] layout ----
__global__ void cvt_x_kernel(const float* __restrict__ x, __bf16* __restrict__ xb) {
    const int i = (blockIdx.x * 256 + threadIdx.x) * 4;
    const float4 v = *reinterpret_cast<const float4*>(x + i);
    __bf16 o[4];
    o[0] = (__bf16)v.x; o[1] = (__bf16)v.y; o[2] = (__bf16)v.z; o[3] = (__bf16)v.w;
    *reinterpret_cast<uint2*>(xb + i) = *reinterpret_cast<const uint2*>(o);
}

// ---- pre-kernel 2: ilogm1[t][b] = 1/ln(e + dts[b][t]) - 1 ----
__global__ void prep_ilog_kernel(const float* __restrict__ dts, float* __restrict__ il) {
    const int idx = blockIdx.x * 256 + threadIdx.x;
    const int b = idx >> 11, t = idx & 2047;
    const float l = __logf(2.718281828459045f + dts[idx]);
    il[t * BAT + b] = __fdividef(1.0f, l) - 1.0f;
}

// ---- pre-kernel 3: xg[d][row=(t,b)][j] = float4{i,f,g,o pre-acts} = x@Wih^T + bih + bhh
// 1024 WGs x 512 thr; wave w owns dims j in [16w,16w+16); 8 M-tiles of 16 rows per WG.
__global__ __launch_bounds__(512, 2) void xg_kernel(
    const __bf16* __restrict__ xb,
    const float* __restrict__ Wih_f, const float* __restrict__ bih_f, const float* __restrict__ bhh_f,
    const float* __restrict__ Wih_r, const float* __restrict__ bih_r, const float* __restrict__ bhh_r,
    float4* __restrict__ xg)
{
    const int tid  = threadIdx.x;
    const int w    = tid >> 6;
    const int lane = tid & 63;
    const int nl   = lane & 15;
    const int q    = lane >> 4;
    const int j    = w * 16 + nl;

    bf16x8 wf[2][4][4];
    f32x4  bg[2][4];
    #pragma unroll
    for (int g = 0; g < 4; ++g) {
        const int row = g * 128 + j;
        #pragma unroll
        for (int kt = 0; kt < 4; ++kt) {
            const int off = row * HID + kt * 32 + q * 8;
            wf[0][g][kt] = cvt8(Wih_f + off);
            wf[1][g][kt] = cvt8(Wih_r + off);
        }
        const float bf = bih_f[row] + bhh_f[row];
        const float br = bih_r[row] + bhh_r[row];
        bg[0][g] = f32x4{bf, bf, bf, bf};
        bg[1][g] = f32x4{br, br, br, br};
    }

    for (int it = 0; it < 8; ++it) {
        const int Mt = it * 1024 + blockIdx.x;          // 8192 M-tiles of 16 rows
        bf16x8 afr[4];
        #pragma unroll
        for (int kt = 0; kt < 4; ++kt)
            afr[kt] = *reinterpret_cast<const bf16x8*>(xb + (size_t)(Mt * 16 + nl) * HID + kt * 32 + q * 8);

        #pragma unroll
        for (int dd = 0; dd < 2; ++dd) {
            f32x4 a0 = MFMA(afr[0], wf[dd][0][0], bg[dd][0]);
            f32x4 a1 = MFMA(afr[0], wf[dd][1][0], bg[dd][1]);
            f32x4 a2 = MFMA(afr[0], wf[dd][2][0], bg[dd][2]);
            f32x4 a3 = MFMA(afr[0], wf[dd][3][0], bg[dd][3]);
            #pragma unroll
            for (int kt = 1; kt < 4; ++kt) {
                a0 = MFMA(afr[kt], wf[dd][0][kt], a0);
                a1 = MFMA(afr[kt], wf[dd][1][kt], a1);
                a2 = MFMA(afr[kt], wf[dd][2][kt], a2);
                a3 = MFMA(afr[kt], wf[dd][3][kt], a3);
            }
            #pragma unroll
            for (int r = 0; r < 4; ++r) {
                const int row = Mt * 16 + 4 * q + r;
                xg[((size_t)dd * SEQ * BAT + row) * HID + j] = float4{a0[r], a1[r], a2[r], a3[r]};
            }
        }
    }
}

// ---- main (dual-group): 16 WGs, 8 chains each (two independent 4-chain groups).
// Per pair-step: {G0,G1} ds_reads -> G0 20 MFMAs -> G1 20 MFMAs -> G0 epilogue
// (overlaps G1 MFMA drain) -> G1 epilogue -> one barrier. x-gate pre-acts come
// precomputed from xg (incl. all biases); gates C-in = 0, cs C-in = bd splat.
// hc tile per group: h(chain c) at row 4c (C reg 0), c at row 4c+1 (C reg 1).
__global__ __launch_bounds__(512, 2) void tlstm_dual(
    const float4* __restrict__ xg,  const float* __restrict__ ilg,
    const float* __restrict__ h0,   const float* __restrict__ c0,
    const float* __restrict__ Whh_f, const float* __restrict__ Wd_f, const float* __restrict__ bd_f,
    const float* __restrict__ Whh_r, const float* __restrict__ Wd_r, const float* __restrict__ bd_r,
    float* __restrict__ out)
{
    const int d    = blockIdx.x >> 3;
    const int b0   = (blockIdx.x & 7) * 8;     // 8 chains: G0=b0..b0+3, G1=b0+4..b0+7
    const int tid  = threadIdx.x;
    const int w    = tid >> 6;
    const int lane = tid & 63;
    const int nl   = lane & 15;
    const int q    = lane >> 4;
    const int j    = w * 16 + nl;

    const float* Whh = d ? Whh_r : Whh_f;
    const float* Wd  = d ? Wd_r  : Wd_f;
    const float* bd  = d ? bd_r  : bd_f;

    __shared__ __align__(16) __bf16 hc[2][2][16][LDSP];   // [grp][p][row][col]

    bf16x8 whh_fr[4][4], wd_fr[4];
    #pragma unroll
    for (int g = 0; g < 4; ++g) {
        const int row = g * 128 + j;
        #pragma unroll
        for (int kt = 0; kt < 4; ++kt)
            whh_fr[g][kt] = cvt8(Whh + row * HID + kt * 32 + q * 8);
    }
    #pragma unroll
    for (int kt = 0; kt < 4; ++kt)
        wd_fr[kt] = cvt8(Wd + j * HID + kt * 32 + q * 8);

    const float bias_d = bd[j];
    const f32x4 bdv = f32x4{bias_d, bias_d, bias_d, bias_d};
    const f32x4 zc  = f32x4{0.0f, 0.0f, 0.0f, 0.0f};

    // initial state: 8 chains; grp = ci>>2, chain-local cl = ci&3
    for (int e = tid; e < 8 * HID; e += 512) {
        const int ci = e >> 7, k = e & 127;
        const int grp = ci >> 2, cl = ci & 3;
        hc[grp][0][cl * 4][k]     = (__bf16)h0[(d * BAT + b0 + ci) * HID + k];
        hc[grp][0][cl * 4 + 1][k] = (__bf16)c0[(d * BAT + b0 + ci) * HID + k];
    }
    float c_st0 = c0[(d * BAT + b0 + q) * HID + j];
    float c_st1 = c0[(d * BAT + b0 + 4 + q) * HID + j];
    __syncthreads();

    const int t0    = d ? (SEQ - 1) : 0;
    const int tstep = d ? -1 : 1;
    const long xgstep = (long)tstep * BAT * HID;        // float4 units per step
    const int  istride = tstep * BAT;
    const int  ostride = tstep * BAT * 256;

    const float4* xg0 = xg + ((size_t)d * SEQ * BAT + (size_t)t0 * BAT + b0 + q) * HID + j;
    const float4* xg1 = xg0 + (size_t)4 * HID;          // chain b0+4+q
    const float*  ip0 = ilg + (size_t)t0 * BAT + b0 + q;
    const float*  ip1 = ip0 + 4;
    float* op0 = out + (size_t)(t0 * BAT + b0 + q) * 256 + d * 128 + j;
    float* op1 = op0 + 4 * 256;

    // rolling prefetch buffers, distance 4 steps (slot = t&3, compile-time via unroll)
    float4 xgb0[4], xgb1[4];
    float  ilb0[4], ilb1[4];
    #pragma unroll
    for (int s = 0; s < 4; ++s) {
        xgb0[s] = xg0[(long)s * xgstep];
        xgb1[s] = xg1[(long)s * xgstep];
        ilb0[s] = ip0[s * istride];
        ilb1[s] = ip1[s * istride];
    }
    const float4* xgl0 = xg0 + 4 * xgstep;
    const float4* xgl1 = xg1 + 4 * xgstep;
    const float*  ill0 = ip0 + 4 * istride;
    const float*  ill1 = ip1 + 4 * istride;

    for (int ts = 0; ts < SEQ; ts += 4) {
        #pragma unroll
        for (int dt = 0; dt < 4; ++dt) {
            const int p  = dt & 1;
            const int pn = p ^ 1;

            // both groups' recurrent-tile reads issued up front
            bf16x8 hcfr0[4], hcfr1[4];
            #pragma unroll
            for (int kt = 0; kt < 4; ++kt)
                hcfr0[kt] = *reinterpret_cast<const bf16x8*>(&hc[0][p][nl][kt * 32 + q * 8]);
            #pragma unroll
            for (int kt = 0; kt < 4; ++kt)
                hcfr1[kt] = *reinterpret_cast<const bf16x8*>(&hc[1][p][nl][kt * 32 + q * 8]);

            // consume slots, then reload (step +4)
            const float4 xv0 = xgb0[dt]; const float il0 = ilb0[dt];
            const float4 xv1 = xgb1[dt]; const float il1 = ilb1[dt];
            xgb0[dt] = *xgl0; xgl0 += xgstep;
            xgb1[dt] = *xgl1; xgl1 += xgstep;
            ilb0[dt] = *ill0; ill0 += istride;
            ilb1[dt] = *ill1; ill1 += istride;

            // G0 MFMAs (cs chain first -> epilogue's serial tanh path starts earliest)
            f32x4 cA0 = MFMA(hcfr0[0], wd_fr[0],     bdv);
            f32x4 a00 = MFMA(hcfr0[0], whh_fr[0][0], zc);
            f32x4 a01 = MFMA(hcfr0[0], whh_fr[1][0], zc);
            f32x4 a02 = MFMA(hcfr0[0], whh_fr[2][0], zc);
            f32x4 a03 = MFMA(hcfr0[0], whh_fr[3][0], zc);
            #pragma unroll
            for (int kt = 1; kt < 4; ++kt) {
                cA0 = MFMA(hcfr0[kt], wd_fr[kt],     cA0);
                a00 = MFMA(hcfr0[kt], whh_fr[0][kt], a00);
                a01 = MFMA(hcfr0[kt], whh_fr[1][kt], a01);
                a02 = MFMA(hcfr0[kt], whh_fr[2][kt], a02);
                a03 = MFMA(hcfr0[kt], whh_fr[3][kt], a03);
            }
            // G1 MFMAs (independent — fill G0's dep-latency tail)
            f32x4 cA1 = MFMA(hcfr1[0], wd_fr[0],     bdv);
            f32x4 a10 = MFMA(hcfr1[0], whh_fr[0][0], zc);
            f32x4 a11 = MFMA(hcfr1[0], whh_fr[1][0], zc);
            f32x4 a12 = MFMA(hcfr1[0], whh_fr[2][0], zc);
            f32x4 a13 = MFMA(hcfr1[0], whh_fr[3][0], zc);
            #pragma unroll
            for (int kt = 1; kt < 4; ++kt) {
                cA1 = MFMA(hcfr1[kt], wd_fr[kt],     cA1);
                a10 = MFMA(hcfr1[kt], whh_fr[0][kt], a10);
                a11 = MFMA(hcfr1[kt], whh_fr[1][kt], a11);
                a12 = MFMA(hcfr1[kt], whh_fr[2][kt], a12);
                a13 = MFMA(hcfr1[kt], whh_fr[3][kt], a13);
            }

            // G0 epilogue (VALU runs while G1 MFMAs drain)
            {
                const float cs   = tanh_f(cA0[1]);
                const float cadj = fmaf(cs, il0, c_st0);
                const float gi   = sig_f(a00[0] + xv0.x);
                const float gf   = sig_f(a01[0] + xv0.y);
                const float gg   = tanh_f(a02[0] + xv0.z);
                const float cn   = gf * cadj + gi * gg;
                hc[0][pn][q * 4 + 1][j] = (__bf16)cn;
                const float go   = sig_f(a03[0] + xv0.w);
                const float hn   = go * tanh_f(cn);
                c_st0 = cn;
                hc[0][pn][q * 4][j] = (__bf16)hn;
                *op0 = hn;
            }
            op0 += ostride;
            // G1 epilogue
            {
                const float cs   = tanh_f(cA1[1]);
                const float cadj = fmaf(cs, il1, c_st1);
                const float gi   = sig_f(a10[0] + xv1.x);
                const float gf   = sig_f(a11[0] + xv1.y);
                const float gg   = tanh_f(a12[0] + xv1.z);
                const float cn   = gf * cadj + gi * gg;
                hc[1][pn][q * 4 + 1][j] = (__bf16)cn;
                const float go   = sig_f(a13[0] + xv1.w);
                const float hn   = go * tanh_f(cn);
                c_st1 = cn;
                hc[1][pn][q * 4][j] = (__bf16)hn;
                *op1 = hn;
            }
            op1 += ostride;

            // order LDS ops only; keep global loads/stores in flight across the barrier
            asm volatile("s_waitcnt lgkmcnt(0)\n\ts_barrier" ::: "memory");
        }
    }
}

// ---- fallback main: R5 kernel verbatim (proven 1658 µs main dispatch) ----
__global__ __launch_bounds__(512, 2) void tlstm_fb(
    const __bf16* __restrict__ xb,   const float* __restrict__ ilg,
    const float* __restrict__ h0,    const float* __restrict__ c0,
    const float* __restrict__ Wih_f, const float* __restrict__ Whh_f,
    const float* __restrict__ bih_f, const float* __restrict__ bhh_f,
    const float* __restrict__ Wd_f,  const float* __restrict__ bd_f,
    const float* __restrict__ Wih_r, const float* __restrict__ Whh_r,
    const float* __restrict__ bih_r, const float* __restrict__ bhh_r,
    const float* __restrict__ Wd_r,  const float* __restrict__ bd_r,
    float* __restrict__ out)
{
    const int d    = blockIdx.x >> 4;
    const int b0   = (blockIdx.x & 15) * 4;
    const int tid  = threadIdx.x;
    const int w    = tid >> 6;
    const int lane = tid & 63;
    const int nl   = lane & 15;
    const int q    = lane >> 4;
    const int j    = w * 16 + nl;

    const float* Wih = d ? Wih_r : Wih_f;
    const float* Whh = d ? Whh_r : Whh_f;
    const float* bih = d ? bih_r : bih_f;
    const float* bhh = d ? bhh_r : bhh_f;
    const float* Wd  = d ? Wd_r  : Wd_f;
    const float* bd  = d ? bd_r  : bd_f;

    __shared__ __align__(16) __bf16 hc_a[2][16][LDSP];

    bf16x8 whh_fr[4][4], wih_fr[4][4], wd_fr[4];
    #pragma unroll
    for (int g = 0; g < 4; ++g) {
        const int row = g * 128 + j;
        #pragma unroll
        for (int kt = 0; kt < 4; ++kt) {
            const int off = row * HID + kt * 32 + q * 8;
            wih_fr[g][kt] = cvt8(Wih + off);
            whh_fr[g][kt] = cvt8(Whh + off);
        }
    }
    #pragma unroll
    for (int kt = 0; kt < 4; ++kt)
        wd_fr[kt] = cvt8(Wd + j * HID + kt * 32 + q * 8);

    f32x4 bgv[4];
    #pragma unroll
    for (int g = 0; g < 4; ++g) {
        const float b = bih[g * 128 + j] + bhh[g * 128 + j];
        bgv[g] = f32x4{b, b, b, b};
    }
    const float bias_d = bd[j];
    const f32x4 bdv = f32x4{bias_d, bias_d, bias_d, bias_d};

    for (int e = tid; e < 4 * HID; e += 512) {
        const int ci = e >> 7, k = e & 127;
        hc_a[0][ci * 4][k]     = (__bf16)h0[(d * BAT + b0 + ci) * HID + k];
        hc_a[0][ci * 4 + 2][k] = (__bf16)c0[(d * BAT + b0 + ci) * HID + k];
    }
    float c_st = c0[(d * BAT + b0 + q) * HID + j];
    __syncthreads();

    const int t0      = d ? (SEQ - 1) : 0;
    const int tstep   = d ? -1 : 1;
    const int xstride = tstep * BAT * HID;
    const int istride = tstep * BAT;
    const int ostride = tstep * BAT * 256;

    const __bf16* xp0 = xb + (size_t)((t0 + tstep * (nl & 3)) * BAT + b0 + (nl >> 2)) * HID + q * 8;
    const float*  ip0 = ilg + (size_t)t0 * BAT + b0 + q;
    float*        op  = out + (size_t)(t0 * BAT + b0 + q) * 256 + d * 128 + j;

    bf16x8 xfrA[4], xfrB[4];
    f32x4  xaccA[4], xaccB[4];
    float  ilA[4], ilB[4];

    {
        bf16x8 t[4];
        #pragma unroll
        for (int kt = 0; kt < 4; ++kt)
            t[kt] = *reinterpret_cast<const bf16x8*>(xp0 + kt * 32);
        xaccA[0] = MFMA(t[0], wih_fr[0][0], bgv[0]);
        xaccA[1] = MFMA(t[0], wih_fr[1][0], bgv[1]);
        xaccA[2] = MFMA(t[0], wih_fr[2][0], bgv[2]);
        xaccA[3] = MFMA(t[0], wih_fr[3][0], bgv[3]);
        #pragma unroll
        for (int kt = 1; kt < 4; ++kt) {
            xaccA[0] = MFMA(t[kt], wih_fr[0][kt], xaccA[0]);
            xaccA[1] = MFMA(t[kt], wih_fr[1][kt], xaccA[1]);
            xaccA[2] = MFMA(t[kt], wih_fr[2][kt], xaccA[2]);
            xaccA[3] = MFMA(t[kt], wih_fr[3][kt], xaccA[3]);
        }
    }
    #pragma unroll
    for (int kt = 0; kt < 4; ++kt) {
        xfrA[kt] = *reinterpret_cast<const bf16x8*>(xp0 + 4 * xstride + kt * 32);
        xfrB[kt] = *reinterpret_cast<const bf16x8*>(xp0 + 8 * xstride + kt * 32);
    }
    #pragma unroll
    for (int dtv = 0; dtv < 4; ++dtv) {
        ilA[dtv] = ip0[dtv * istride];
        ilB[dtv] = ip0[(4 + dtv) * istride];
    }
    const __bf16* xpl = xp0 + 8 * xstride;
    const float*  ipl = ip0 + 8 * istride;

    auto chunk = [&](f32x4 (&xu)[4], f32x4 (&xnb)[4],
                     bf16x8 (&xfS)[4], bf16x8 (&xfL)[4],
                     float (&ilCur)[4]) __attribute__((always_inline)) {
        // chunk-head burst for NEXT chunk (dense, 4 independent chains of 4)
        f32x4 n0 = MFMA(xfS[0], wih_fr[0][0], bgv[0]);
        f32x4 n1 = MFMA(xfS[0], wih_fr[1][0], bgv[1]);
        f32x4 n2 = MFMA(xfS[0], wih_fr[2][0], bgv[2]);
        f32x4 n3 = MFMA(xfS[0], wih_fr[3][0], bgv[3]);
        #pragma unroll
        for (int kt = 1; kt < 4; ++kt) {
            n0 = MFMA(xfS[kt], wih_fr[0][kt], n0);
            n1 = MFMA(xfS[kt], wih_fr[1][kt], n1);
            n2 = MFMA(xfS[kt], wih_fr[2][kt], n2);
            n3 = MFMA(xfS[kt], wih_fr[3][kt], n3);
        }
        xnb[0] = n0; xnb[1] = n1; xnb[2] = n2; xnb[3] = n3;

        #pragma unroll
        for (int dt = 0; dt < 4; ++dt) {
            const int p  = dt & 1;
            const int pn = p ^ 1;
            const int hr = dt;
            const int cr = (dt + 2) & 3;

            const float il_use = ilCur[dt];

            bf16x8 hcfr[4];
            #pragma unroll
            for (int kt = 0; kt < 4; ++kt)
                hcfr[kt] = *reinterpret_cast<const bf16x8*>(&hc_a[p][nl][kt * 32 + q * 8]);

            xfL[dt]   = *reinterpret_cast<const bf16x8*>(xpl + dt * 32);
            ilCur[dt] = ipl[dt * istride];

            f32x4 cA = MFMA(hcfr[0], wd_fr[0],     bdv);
            f32x4 g0 = MFMA(hcfr[0], whh_fr[0][0], xu[0]);
            f32x4 g1 = MFMA(hcfr[0], whh_fr[1][0], xu[1]);
            f32x4 g2 = MFMA(hcfr[0], whh_fr[2][0], xu[2]);
            f32x4 g3 = MFMA(hcfr[0], whh_fr[3][0], xu[3]);
            #pragma unroll
            for (int kt = 1; kt < 4; ++kt) {
                cA = MFMA(hcfr[kt], wd_fr[kt],      cA);
                g0 = MFMA(hcfr[kt], whh_fr[0][kt],  g0);
                g1 = MFMA(hcfr[kt], whh_fr[1][kt],  g1);
                g2 = MFMA(hcfr[kt], whh_fr[2][kt],  g2);
                g3 = MFMA(hcfr[kt], whh_fr[3][kt],  g3);
            }

            {
                const float cs   = tanh_f(cA[cr]);
                const float cadj = fmaf(cs, il_use, c_st);
                const float gf   = sig_f(g1[hr]);
                const float gi   = sig_f(g0[hr]);
                const float gg   = tanh_f(g2[hr]);
                const float cn   = gf * cadj + gi * gg;
                hc_a[pn][q * 4 + ((dt + 3) & 3)][j] = (__bf16)cn;
                const float go   = sig_f(g3[hr]);
                const float hn   = go * tanh_f(cn);
                c_st = cn;
                hc_a[pn][q * 4 + ((dt + 1) & 3)][j] = (__bf16)hn;
                *op = hn;
            }
            op += ostride;

            asm volatile("s_waitcnt lgkmcnt(0)\n\ts_barrier" ::: "memory");
        }
        xpl += 4 * xstride;
        ipl += 4 * istride;
    };

    // NOTE: fb uses R4/R5 row rotation layout: h at 4c+dt, c at 4c+((dt+2)&3)
    for (int tc = 0; tc < SEQ / 4; tc += 2) {
        chunk(xaccA, xaccB, xfrA, xfrB, ilA);
        chunk(xaccB, xaccA, xfrB, xfrA, ilB);
    }
}

extern "C" void kernel_launch(void* const* d_in, const int* in_sizes, int n_in,
                              void* d_out, int out_size, void* d_ws, size_t ws_size,
                              hipStream_t stream) {
    const float* x     = (const float*)d_in[0];
    const float* h0    = (const float*)d_in[1];
    const float* c0    = (const float*)d_in[2];
    const float* dts   = (const float*)d_in[3];
    const float* Wih_f = (const float*)d_in[4];
    const float* Whh_f = (const float*)d_in[5];
    const float* bih_f = (const float*)d_in[6];
    const float* bhh_f = (const float*)d_in[7];
    const float* Wd_f  = (const float*)d_in[8];
    const float* bd_f  = (const float*)d_in[9];
    const float* Wih_r = (const float*)d_in[10];
    const float* Whh_r = (const float*)d_in[11];
    const float* bih_r = (const float*)d_in[12];
    const float* bhh_r = (const float*)d_in[13];
    const float* Wd_r  = (const float*)d_in[14];
    const float* bd_r  = (const float*)d_in[15];
    float* out = (float*)d_out;

    __bf16* xbuf = (__bf16*)((char*)d_ws + XB_OFF);
    float*  il   = (float*)((char*)d_ws + IL_OFF);

    cvt_x_kernel<<<16384, 256, 0, stream>>>(x, xbuf);
    prep_ilog_kernel<<<512, 256, 0, stream>>>(dts, il);

    if (ws_size >= WS_NEED) {
        float4* xg = (float4*)((char*)d_ws + XG_OFF);
        xg_kernel<<<1024, 512, 0, stream>>>(xbuf, Wih_f, bih_f, bhh_f,
                                            Wih_r, bih_r, bhh_r, xg);
        tlstm_dual<<<16, 512, 0, stream>>>(xg, il, h0, c0,
                                           Whh_f, Wd_f, bd_f,
                                           Whh_r, Wd_r, bd_r, out);
    } else {
        tlstm_fb<<<32, 512, 0, stream>>>(xbuf, il, h0, c0,
                                         Wih_f, Whh_f, bih_f, bhh_f, Wd_f, bd_f,
                                         Wih_r, Whh_r, bih_r, bhh_r, Wd_r, bd_r,
                                         out);
    }
}

// Round 8
// 2587.344 us; speedup vs baseline: 1.0122x; 1.0122x over previous
//
#include <hip/hip_runtime.h>
#include <hip/hip_bf16.h>

#define SEQ  2048
#define BAT  64
#define HID  128
#define LDSP 136   // padded LDS row: 272 B

// workspace layout (36 MiB proven available; 1 MiB guard before XB)
#define XB_OFF  (1u << 20)            // bf16 x, 32 MiB
#define IL_OFF  (35u << 20)           // f32 ilogm1[t][b], 512 KiB

typedef __bf16 bf16x8 __attribute__((ext_vector_type(8)));
typedef float  f32x4  __attribute__((ext_vector_type(4)));

#define MFMA(a,b,c) __builtin_amdgcn_mfma_f32_16x16x32_bf16((a),(b),(c),0,0,0)

__device__ __forceinline__ float sig_f(float x) {
    return __fdividef(1.0f, 1.0f + __expf(-x));
}
__device__ __forceinline__ float tanh_f(float x) {
    return 1.0f - __fdividef(2.0f, 1.0f + __expf(2.0f * x));
}
__device__ __forceinline__ bf16x8 cvt8(const float* p) {
    bf16x8 r;
    #pragma unroll
    for (int i = 0; i < 8; ++i) r[i] = (__bf16)p[i];
    return r;
}

// ---- pre-kernel 1: x f32 -> bf16, same [S][B][I] layout ----
__global__ void cvt_x_kernel(const float* __restrict__ x, __bf16* __restrict__ xb) {
    const int i = (blockIdx.x * 256 + threadIdx.x) * 4;
    const float4 v = *reinterpret_cast<const float4*>(x + i);
    __bf16 o[4];
    o[0] = (__bf16)v.x; o[1] = (__bf16)v.y; o[2] = (__bf16)v.z; o[3] = (__bf16)v.w;
    *reinterpret_cast<uint2*>(xb + i) = *reinterpret_cast<const uint2*>(o);
}

// ---- pre-kernel 2: ilogm1[t][b] = 1/ln(e + dts[b][t]) - 1 ----
__global__ void prep_ilog_kernel(const float* __restrict__ dts, float* __restrict__ il) {
    const int idx = blockIdx.x * 256 + threadIdx.x;
    const int b = idx >> 11, t = idx & 2047;
    const float l = __logf(2.718281828459045f + dts[idx]);
    il[t * BAT + b] = __fdividef(1.0f, l) - 1.0f;
}

// 16 WGs: blockIdx = dir*8 + batch_tile; each WG owns 8 chains; 8 waves, wave w
// owns gate dims j in [16w, 16w+16).
//
// FULL-DENSITY hc TILE (R8): h and c interleaved as rows of ONE 16-row tile:
// at step parity pt, h(chain c) lives at row 2c+pt, c(chain c) at row 2c+1-pt;
// each step writes next parity's rows into the other buffer. 8 chains/tile,
// ZERO pad rows. One set of 4 ds_read_b128 feeds gates (h-rows) AND cs (c-rows).
// Lane q's C regs: gates real at reg 2ch+pt, cs real at reg 2ch+1-pt for its
// two chains ch=0,1 (global chains 2q, 2q+1). D row m sums only A row m, so
// h-rows never contaminate cs outputs and vice versa.
//
// x-BURST per 2-step pair: A-row 2c+tau = x(chain c, pair_base+tau); ONE dense
// 16-MFMA burst yields x-pre for BOTH steps: regs {0,2} = step A, {1,3} =
// step B, consumed VERBATIM as gate C-in at each step (D != C preserves xacc).
// Biases applied as scalars in the epilogue (saves 28 regs vs splat C-init).
//
// Per wave per step: 20 recurrent + 8 amortized burst = 28 for 8 chains
// (R5: 24 for 4 chains -> per-chain MFMA work halved).
__global__ __launch_bounds__(512, 2) void tlstm_main(
    const __bf16* __restrict__ xb,   const float* __restrict__ ilg,
    const float* __restrict__ h0,    const float* __restrict__ c0,
    const float* __restrict__ Wih_f, const float* __restrict__ Whh_f,
    const float* __restrict__ bih_f, const float* __restrict__ bhh_f,
    const float* __restrict__ Wd_f,  const float* __restrict__ bd_f,
    const float* __restrict__ Wih_r, const float* __restrict__ Whh_r,
    const float* __restrict__ bih_r, const float* __restrict__ bhh_r,
    const float* __restrict__ Wd_r,  const float* __restrict__ bd_r,
    float* __restrict__ out)
{
    const int d    = blockIdx.x >> 3;
    const int b0   = (blockIdx.x & 7) * 8;     // 8 chains per WG
    const int tid  = threadIdx.x;
    const int w    = tid >> 6;
    const int lane = tid & 63;
    const int nl   = lane & 15;
    const int q    = lane >> 4;
    const int j    = w * 16 + nl;

    const float* Wih = d ? Wih_r : Wih_f;
    const float* Whh = d ? Whh_r : Whh_f;
    const float* bih = d ? bih_r : bih_f;
    const float* bhh = d ? bhh_r : bhh_f;
    const float* Wd  = d ? Wd_r  : Wd_f;
    const float* bd  = d ? bd_r  : bd_f;

    __shared__ __align__(16) __bf16 hc[2][16][LDSP];

    // resident weight B-frags: B[k][n] = W[n][k]; lane: n=nl(->j), k = kt*32 + q*8 ..+8
    bf16x8 whh_fr[4][4], wih_fr[4][4], wd_fr[4];
    #pragma unroll
    for (int g = 0; g < 4; ++g) {
        const int row = g * 128 + j;
        #pragma unroll
        for (int kt = 0; kt < 4; ++kt) {
            const int off = row * HID + kt * 32 + q * 8;
            wih_fr[g][kt] = cvt8(Wih + off);
            whh_fr[g][kt] = cvt8(Whh + off);
        }
    }
    #pragma unroll
    for (int kt = 0; kt < 4; ++kt)
        wd_fr[kt] = cvt8(Wd + j * HID + kt * 32 + q * 8);

    // biases as scalars (added in epilogue, f32)
    const float bg0 = bih[0 * 128 + j] + bhh[0 * 128 + j];
    const float bg1 = bih[1 * 128 + j] + bhh[1 * 128 + j];
    const float bg2 = bih[2 * 128 + j] + bhh[2 * 128 + j];
    const float bg3 = bih[3 * 128 + j] + bhh[3 * 128 + j];
    const float bd_s = bd[j];
    const f32x4 zc = f32x4{0.0f, 0.0f, 0.0f, 0.0f};

    // initial state (step 0 has pt=0): h(c) at row 2c, c(c) at row 2c+1, buffer 0
    for (int e = tid; e < 8 * HID; e += 512) {
        const int ci = e >> 7, k = e & 127;
        hc[0][2 * ci][k]     = (__bf16)h0[(d * BAT + b0 + ci) * HID + k];
        hc[0][2 * ci + 1][k] = (__bf16)c0[(d * BAT + b0 + ci) * HID + k];
    }
    float c_s0 = c0[(d * BAT + b0 + 2 * q) * HID + j];       // lane's chain 2q
    float c_s1 = c0[(d * BAT + b0 + 2 * q + 1) * HID + j];   // lane's chain 2q+1
    __syncthreads();

    const int t0      = d ? (SEQ - 1) : 0;
    const int tstep   = d ? -1 : 1;
    const int xstride = tstep * BAT * HID;
    const int istride = tstep * BAT;
    const int ostride = tstep * BAT * 256;

    // burst A-row nl -> (chain nl>>1, tau nl&1)
    const __bf16* xp0 = xb + (size_t)((t0 + tstep * (nl & 1)) * BAT + b0 + (nl >> 1)) * HID + q * 8;
    const float*  ip0 = ilg + (size_t)t0 * BAT + b0 + 2 * q;
    float*        op  = out + (size_t)(t0 * BAT + b0 + 2 * q) * 256 + d * 128 + j;

    // x frags: single buffer, consume-at-pair-head then reload for pair+1
    bf16x8 xfr[4];
    #pragma unroll
    for (int kt = 0; kt < 4; ++kt)
        xfr[kt] = *reinterpret_cast<const bf16x8*>(xp0 + kt * 32);
    const __bf16* xpn = xp0 + 2 * xstride;

    // il double-buffer by pair: [tau] = float2{chain 2q, chain 2q+1}
    float2 ilP[2], ilQ[2];
    ilP[0] = *reinterpret_cast<const float2*>(ip0);
    ilP[1] = *reinterpret_cast<const float2*>(ip0 + istride);
    const float* ipn = ip0 + 2 * istride;

    auto pair = [&](float2 (&ilc)[2], float2 (&iln)[2]) __attribute__((always_inline)) {
        f32x4 xa0, xa1, xa2, xa3;   // x-pre: regs {0,2} step A, {1,3} step B
        // ===== step A (pt=0): read hc[0], write hc[1] =====
        {
            bf16x8 hcfr[4];
            #pragma unroll
            for (int kt = 0; kt < 4; ++kt)
                hcfr[kt] = *reinterpret_cast<const bf16x8*>(&hc[0][nl][kt * 32 + q * 8]);

            // burst (no LDS dependency -> fills ds_read latency)
            xa0 = MFMA(xfr[0], wih_fr[0][0], zc);
            xa1 = MFMA(xfr[0], wih_fr[1][0], zc);
            xa2 = MFMA(xfr[0], wih_fr[2][0], zc);
            xa3 = MFMA(xfr[0], wih_fr[3][0], zc);
            #pragma unroll
            for (int kt = 1; kt < 4; ++kt) {
                xa0 = MFMA(xfr[kt], wih_fr[0][kt], xa0);
                xa1 = MFMA(xfr[kt], wih_fr[1][kt], xa1);
                xa2 = MFMA(xfr[kt], wih_fr[2][kt], xa2);
                xa3 = MFMA(xfr[kt], wih_fr[3][kt], xa3);
            }

            // recurrent: C-in = xacc verbatim (D != C preserves xacc for step B)
            f32x4 cA = MFMA(hcfr[0], wd_fr[0],     zc);
            f32x4 g0 = MFMA(hcfr[0], whh_fr[0][0], xa0);
            f32x4 g1 = MFMA(hcfr[0], whh_fr[1][0], xa1);
            f32x4 g2 = MFMA(hcfr[0], whh_fr[2][0], xa2);
            f32x4 g3 = MFMA(hcfr[0], whh_fr[3][0], xa3);
            #pragma unroll
            for (int kt = 1; kt < 4; ++kt) {
                cA = MFMA(hcfr[kt], wd_fr[kt],     cA);
                g0 = MFMA(hcfr[kt], whh_fr[0][kt], g0);
                g1 = MFMA(hcfr[kt], whh_fr[1][kt], g1);
                g2 = MFMA(hcfr[kt], whh_fr[2][kt], g2);
                g3 = MFMA(hcfr[kt], whh_fr[3][kt], g3);
            }

            // epilogue ch0 (chain 2q): gates reg 0, cs reg 1; writes c->row 4q, h->row 4q+1
            {
                const float cs   = tanh_f(cA[1] + bd_s);
                const float cadj = fmaf(cs, ilc[0].x, c_s0);
                const float gi   = sig_f(g0[0] + bg0);
                const float gf   = sig_f(g1[0] + bg1);
                const float gg   = tanh_f(g2[0] + bg2);
                const float cn   = gf * cadj + gi * gg;
                hc[1][4 * q + 0][j] = (__bf16)cn;
                const float go   = sig_f(g3[0] + bg3);
                const float hn   = go * tanh_f(cn);
                c_s0 = cn;
                hc[1][4 * q + 1][j] = (__bf16)hn;
                op[0] = hn;
            }
            // epilogue ch1 (chain 2q+1): gates reg 2, cs reg 3; c->row 4q+2, h->row 4q+3
            {
                const float cs   = tanh_f(cA[3] + bd_s);
                const float cadj = fmaf(cs, ilc[0].y, c_s1);
                const float gi   = sig_f(g0[2] + bg0);
                const float gf   = sig_f(g1[2] + bg1);
                const float gg   = tanh_f(g2[2] + bg2);
                const float cn   = gf * cadj + gi * gg;
                hc[1][4 * q + 2][j] = (__bf16)cn;
                const float go   = sig_f(g3[2] + bg3);
                const float hn   = go * tanh_f(cn);
                c_s1 = cn;
                hc[1][4 * q + 3][j] = (__bf16)hn;
                op[256] = hn;
            }
            op += ostride;
            asm volatile("s_waitcnt lgkmcnt(0)\n\ts_barrier" ::: "memory");
        }
        // ===== step B (pt=1): read hc[1], write hc[0] =====
        {
            bf16x8 hcfr[4];
            #pragma unroll
            for (int kt = 0; kt < 4; ++kt)
                hcfr[kt] = *reinterpret_cast<const bf16x8*>(&hc[1][nl][kt * 32 + q * 8]);

            // reloads for pair+1 (fire-and-forget; fills part of ds latency)
            #pragma unroll
            for (int kt = 0; kt < 4; ++kt)
                xfr[kt] = *reinterpret_cast<const bf16x8*>(xpn + kt * 32);
            xpn += 2 * xstride;
            iln[0] = *reinterpret_cast<const float2*>(ipn);
            iln[1] = *reinterpret_cast<const float2*>(ipn + istride);
            ipn += 2 * istride;

            f32x4 cA = MFMA(hcfr[0], wd_fr[0],     zc);
            f32x4 g0 = MFMA(hcfr[0], whh_fr[0][0], xa0);
            f32x4 g1 = MFMA(hcfr[0], whh_fr[1][0], xa1);
            f32x4 g2 = MFMA(hcfr[0], whh_fr[2][0], xa2);
            f32x4 g3 = MFMA(hcfr[0], whh_fr[3][0], xa3);
            #pragma unroll
            for (int kt = 1; kt < 4; ++kt) {
                cA = MFMA(hcfr[kt], wd_fr[kt],     cA);
                g0 = MFMA(hcfr[kt], whh_fr[0][kt], g0);
                g1 = MFMA(hcfr[kt], whh_fr[1][kt], g1);
                g2 = MFMA(hcfr[kt], whh_fr[2][kt], g2);
                g3 = MFMA(hcfr[kt], whh_fr[3][kt], g3);
            }

            // epilogue ch0: gates reg 1, cs reg 0; writes c->row 4q+1, h->row 4q
            {
                const float cs   = tanh_f(cA[0] + bd_s);
                const float cadj = fmaf(cs, ilc[1].x, c_s0);
                const float gi   = sig_f(g0[1] + bg0);
                const float gf   = sig_f(g1[1] + bg1);
                const float gg   = tanh_f(g2[1] + bg2);
                const float cn   = gf * cadj + gi * gg;
                hc[0][4 * q + 1][j] = (__bf16)cn;
                const float go   = sig_f(g3[1] + bg3);
                const float hn   = go * tanh_f(cn);
                c_s0 = cn;
                hc[0][4 * q + 0][j] = (__bf16)hn;
                op[0] = hn;
            }
            // epilogue ch1: gates reg 3, cs reg 2; c->row 4q+3, h->row 4q+2
            {
                const float cs   = tanh_f(cA[2] + bd_s);
                const float cadj = fmaf(cs, ilc[1].y, c_s1);
                const float gi   = sig_f(g0[3] + bg0);
                const float gf   = sig_f(g1[3] + bg1);
                const float gg   = tanh_f(g2[3] + bg2);
                const float cn   = gf * cadj + gi * gg;
                hc[0][4 * q + 3][j] = (__bf16)cn;
                const float go   = sig_f(g3[3] + bg3);
                const float hn   = go * tanh_f(cn);
                c_s1 = cn;
                hc[0][4 * q + 2][j] = (__bf16)hn;
                op[256] = hn;
            }
            op += ostride;
            asm volatile("s_waitcnt lgkmcnt(0)\n\ts_barrier" ::: "memory");
        }
    };

    for (int ts = 0; ts < SEQ; ts += 4) {
        pair(ilP, ilQ);
        pair(ilQ, ilP);
    }
}

extern "C" void kernel_launch(void* const* d_in, const int* in_sizes, int n_in,
                              void* d_out, int out_size, void* d_ws, size_t ws_size,
                              hipStream_t stream) {
    const float* x     = (const float*)d_in[0];
    const float* h0    = (const float*)d_in[1];
    const float* c0    = (const float*)d_in[2];
    const float* dts   = (const float*)d_in[3];
    const float* Wih_f = (const float*)d_in[4];
    const float* Whh_f = (const float*)d_in[5];
    const float* bih_f = (const float*)d_in[6];
    const float* bhh_f = (const float*)d_in[7];
    const float* Wd_f  = (const float*)d_in[8];
    const float* bd_f  = (const float*)d_in[9];
    const float* Wih_r = (const float*)d_in[10];
    const float* Whh_r = (const float*)d_in[11];
    const float* bih_r = (const float*)d_in[12];
    const float* bhh_r = (const float*)d_in[13];
    const float* Wd_r  = (const float*)d_in[14];
    const float* bd_r  = (const float*)d_in[15];
    float* out = (float*)d_out;

    __bf16* xbuf = (__bf16*)((char*)d_ws + XB_OFF);
    float*  il   = (float*)((char*)d_ws + IL_OFF);

    cvt_x_kernel<<<16384, 256, 0, stream>>>(x, xbuf);
    prep_ilog_kernel<<<512, 256, 0, stream>>>(dts, il);

    tlstm_main<<<16, 512, 0, stream>>>(xbuf, il, h0, c0,
                                       Wih_f, Whh_f, bih_f, bhh_f, Wd_f, bd_f,
                                       Wih_r, Whh_r, bih_r, bhh_r, Wd_r, bd_r,
                                       out);
}

// Round 9
// 2170.235 us; speedup vs baseline: 1.2067x; 1.1922x over previous
//
#include <hip/hip_runtime.h>
#include <hip/hip_bf16.h>

#define SEQ  2048
#define BAT  64
#define HID  128
#define LDSP 136   // padded LDS row: 272 B

// workspace layout (36 MiB proven; 1 MiB guard before XB for bwd OOB prefetch)
#define XB_OFF  (1u << 20)                       // bf16 x, 32 MiB
#define IL_OFF  (35u << 20)                      // f32 ilogm1[t][b], 512 KiB
#define WB_OFF  ((35u << 20) + (512u << 10))     // bf16 Wih[2][512][128], 256 KiB

typedef __bf16 bf16x8 __attribute__((ext_vector_type(8)));
typedef float  f32x4  __attribute__((ext_vector_type(4)));

#define MFMA(a,b,c) __builtin_amdgcn_mfma_f32_16x16x32_bf16((a),(b),(c),0,0,0)

__device__ __forceinline__ float sig_f(float x) {
    return __fdividef(1.0f, 1.0f + __expf(-x));
}
__device__ __forceinline__ float tanh_f(float x) {
    return 1.0f - __fdividef(2.0f, 1.0f + __expf(2.0f * x));
}
__device__ __forceinline__ bf16x8 cvt8(const float* p) {
    bf16x8 r;
    #pragma unroll
    for (int i = 0; i < 8; ++i) r[i] = (__bf16)p[i];
    return r;
}

// ---- pre-kernel 1: x f32 -> bf16, same [S][B][I] layout ----
__global__ void cvt_x_kernel(const float* __restrict__ x, __bf16* __restrict__ xb) {
    const int i = (blockIdx.x * 256 + threadIdx.x) * 4;
    const float4 v = *reinterpret_cast<const float4*>(x + i);
    __bf16 o[4];
    o[0] = (__bf16)v.x; o[1] = (__bf16)v.y; o[2] = (__bf16)v.z; o[3] = (__bf16)v.w;
    *reinterpret_cast<uint2*>(xb + i) = *reinterpret_cast<const uint2*>(o);
}

// ---- pre-kernel 2: ilogm1[t][b] = 1/ln(e + dts[b][t]) - 1 ----
__global__ void prep_ilog_kernel(const float* __restrict__ dts, float* __restrict__ il) {
    const int idx = blockIdx.x * 256 + threadIdx.x;
    const int b = idx >> 11, t = idx & 2047;
    const float l = __logf(2.718281828459045f + dts[idx]);
    il[t * BAT + b] = __fdividef(1.0f, l) - 1.0f;
}

// ---- pre-kernel 3: Wih f32 -> bf16 in ws (producers stream frags from L2) ----
__global__ void cvt_w_kernel(const float* __restrict__ Wf, const float* __restrict__ Wr,
                             __bf16* __restrict__ wb) {
    const int i = (blockIdx.x * 256 + threadIdx.x) * 4;   // 131072 elems, grid 128
    const int half = 512 * HID;
    const float* src = (i < half) ? Wf : Wr;
    const int off = (i < half) ? i : (i - half);
    const float4 v = *reinterpret_cast<const float4*>(src + off);
    __bf16 o[4];
    o[0] = (__bf16)v.x; o[1] = (__bf16)v.y; o[2] = (__bf16)v.z; o[3] = (__bf16)v.w;
    *reinterpret_cast<uint2*>(wb + i) = *reinterpret_cast<const uint2*>(o);
}

// 32 WGs x 768 thr (12 waves, 3/SIMD, <=170 regs/wave).
// waves 0-7: EPI — R4's proven chunk (row-rotated hc tile, 20 recurrent MFMA/step),
//   gate C-in = 0, x-pre-acts added in the f32 epilogue from LDS pa.
// waves 8-11: PRODUCER — wave 8+p owns gate p (rows [128p,128p+128)). Per chunk:
//   time-batched x-burst (A-row = 4*chain+dt, 16 rows full density) = 32 MFMAs
//   spread 8/interval (kt=interval), Wih bf16 frags streamed from ws in a kt-ring.
//   Writes pre-acts for chunk c+1 into pa at interval 3 (slots 0-2) with slot 3
//   ping-ponged by chunk parity (5-slot buffer) -> race-free under the per-step
//   barrier without double-buffering the whole thing.
// Per SIMD/step: 2 epi x 20 + 1 prod x 8 = 48 MFMA (issue conserved vs R5), but
// producer MFMAs are barrier-decoupled -> they pack epi's ds-latency + epilogue
// idle (the ~718 cy/step R5 couldn't fill).
__global__ __launch_bounds__(768, 3) void tlstm_main(
    const __bf16* __restrict__ xb,   const __bf16* __restrict__ wihb,
    const float* __restrict__ ilg,
    const float* __restrict__ h0,    const float* __restrict__ c0,
    const float* __restrict__ Whh_f, const float* __restrict__ Wd_f, const float* __restrict__ bd_f,
    const float* __restrict__ bih_f, const float* __restrict__ bhh_f,
    const float* __restrict__ Whh_r, const float* __restrict__ Wd_r, const float* __restrict__ bd_r,
    const float* __restrict__ bih_r, const float* __restrict__ bhh_r,
    float* __restrict__ out)
{
    const int d    = blockIdx.x >> 4;
    const int b0   = (blockIdx.x & 15) * 4;
    const int tid  = threadIdx.x;
    const int wv   = tid >> 6;
    const int lane = tid & 63;
    const int nl   = lane & 15;
    const int q    = lane >> 4;

    __shared__ __align__(16) __bf16 hc_a[2][16][LDSP];
    __shared__ __align__(16) float  pa[5][4][HID][4];   // [slot][chain][dim][gate], 40 KB

    const int t0      = d ? (SEQ - 1) : 0;
    const int tstep   = d ? -1 : 1;
    const int xstride = tstep * BAT * HID;
    const int istride = tstep * BAT;
    const int ostride = tstep * BAT * 256;

    if (wv >= 8) {
        // ================= PRODUCER: gate p =================
        const int p = wv - 8;
        const float* bih = d ? bih_r : bih_f;
        const float* bhh = d ? bhh_r : bhh_f;
        // frag base: B col n=nl -> gate-row 128p+16t+nl; k = kt*32 + q*8
        const __bf16* wbp = wihb + (size_t)d * 512 * HID + (size_t)(p * 128 + nl) * HID + q * 8;

        float bgp[8];
        #pragma unroll
        for (int t = 0; t < 8; ++t) {
            const int r = p * 128 + 16 * t + nl;
            bgp[t] = bih[r] + bhh[r];
        }

        // x A-row = 4*chain + dt: chain = nl>>2, dt = nl&3 (R4 burst layout)
        const __bf16* xp0 = xb + (size_t)((t0 + tstep * (nl & 3)) * BAT + b0 + (nl >> 2)) * HID + q * 8;
        bf16x8 xfr[4];
        #pragma unroll
        for (int kt = 0; kt < 4; ++kt)
            xfr[kt] = *reinterpret_cast<const bf16x8*>(xp0 + kt * 32);

        f32x4 acc[8];
        // prologue: build chunk 0 into slots {0,1,2,3}
        #pragma unroll
        for (int kt = 0; kt < 4; ++kt) {
            bf16x8 wt[8];
            #pragma unroll
            for (int t = 0; t < 8; ++t)
                wt[t] = *reinterpret_cast<const bf16x8*>(wbp + (16 * t) * HID + kt * 32);
            #pragma unroll
            for (int t = 0; t < 8; ++t) {
                if (kt == 0) {
                    const f32x4 bsp = f32x4{bgp[t], bgp[t], bgp[t], bgp[t]};
                    acc[t] = MFMA(xfr[0], wt[t], bsp);
                } else {
                    acc[t] = MFMA(xfr[kt], wt[t], acc[t]);
                }
            }
        }
        #pragma unroll
        for (int t = 0; t < 8; ++t) {
            const int dim = 16 * t + nl;
            #pragma unroll
            for (int r = 0; r < 4; ++r)
                pa[r][q][dim][p] = acc[t][r];   // chunk 0 slot3-parity = 3
        }
        // reload xfr with chunk 1; xpn then targets chunk 2
        const __bf16* xpn = xp0 + 4 * xstride;
        #pragma unroll
        for (int kt = 0; kt < 4; ++kt)
            xfr[kt] = *reinterpret_cast<const bf16x8*>(xpn + kt * 32);
        xpn += 4 * xstride;

        // kt-frag ring: wfA holds kt=0 entering each chunk
        bf16x8 wfA[8], wfB[8];
        #pragma unroll
        for (int t = 0; t < 8; ++t)
            wfA[t] = *reinterpret_cast<const bf16x8*>(wbp + (16 * t) * HID);

        __syncthreads();

        auto pstep = [&](int tc, int dt, bf16x8 (&cur)[8], bf16x8 (&nxt)[8])
            __attribute__((always_inline)) {
            // 8 MFMAs, kt = dt (accumulating chunk tc+1's pre-acts)
            if (dt == 0) {
                #pragma unroll
                for (int t = 0; t < 8; ++t) {
                    const f32x4 bsp = f32x4{bgp[t], bgp[t], bgp[t], bgp[t]};
                    acc[t] = MFMA(xfr[0], cur[t], bsp);
                }
            } else {
                #pragma unroll
                for (int t = 0; t < 8; ++t)
                    acc[t] = MFMA(xfr[dt], cur[t], acc[t]);
            }
            // ring-load next kt's frags (L2-hot, chunk-invariant weights)
            const int ktn = (dt + 1) & 3;
            #pragma unroll
            for (int t = 0; t < 8; ++t)
                nxt[t] = *reinterpret_cast<const bf16x8*>(wbp + (16 * t) * HID + ktn * 32);
            // reload x slice dt for chunk tc+2 (use-then-reload, R4 distance)
            xfr[dt] = *reinterpret_cast<const bf16x8*>(xpn + dt * 32);
            if (dt == 3) {
                const int s3 = 3 + ((tc + 1) & 1);
                #pragma unroll
                for (int t = 0; t < 8; ++t) {
                    const int dim = 16 * t + nl;
                    pa[0][q][dim][p]  = acc[t][0];
                    pa[1][q][dim][p]  = acc[t][1];
                    pa[2][q][dim][p]  = acc[t][2];
                    pa[s3][q][dim][p] = acc[t][3];
                }
            }
            asm volatile("s_waitcnt lgkmcnt(0)\n\ts_barrier" ::: "memory");
        };

        for (int tc = 0; tc < SEQ / 4; ++tc) {
            pstep(tc, 0, wfA, wfB);
            pstep(tc, 1, wfB, wfA);
            pstep(tc, 2, wfA, wfB);
            pstep(tc, 3, wfB, wfA);
            xpn += 4 * xstride;
        }
    } else {
        // ================= EPI: dims j = wv*16 + nl =================
        const int j = wv * 16 + nl;
        const float* Whh = d ? Whh_r : Whh_f;
        const float* Wd  = d ? Wd_r  : Wd_f;
        const float* bd  = d ? bd_r  : bd_f;

        bf16x8 whh_fr[4][4], wd_fr[4];
        #pragma unroll
        for (int g = 0; g < 4; ++g) {
            const int row = g * 128 + j;
            #pragma unroll
            for (int kt = 0; kt < 4; ++kt)
                whh_fr[g][kt] = cvt8(Whh + row * HID + kt * 32 + q * 8);
        }
        #pragma unroll
        for (int kt = 0; kt < 4; ++kt)
            wd_fr[kt] = cvt8(Wd + j * HID + kt * 32 + q * 8);

        const float bias_d = bd[j];
        const f32x4 bdv = f32x4{bias_d, bias_d, bias_d, bias_d};
        const f32x4 zc  = f32x4{0.0f, 0.0f, 0.0f, 0.0f};

        // initial state (step 0, dt=0): h at rows 4c+0, c at rows 4c+2 (R4 rotation)
        {
            const int ci = tid >> 7, k = tid & 127;     // tid < 512 here
            hc_a[0][ci * 4][k]     = (__bf16)h0[(d * BAT + b0 + ci) * HID + k];
            hc_a[0][ci * 4 + 2][k] = (__bf16)c0[(d * BAT + b0 + ci) * HID + k];
        }
        float c_st = c0[(d * BAT + b0 + q) * HID + j];

        const float* ip0 = ilg + (size_t)t0 * BAT + b0 + q;
        float*       op  = out + (size_t)(t0 * BAT + b0 + q) * 256 + d * 128 + j;

        float ilA[4], ilB[4];
        #pragma unroll
        for (int dtv = 0; dtv < 4; ++dtv) {
            ilA[dtv] = ip0[dtv * istride];
            ilB[dtv] = ip0[(4 + dtv) * istride];
        }
        const float* ipl = ip0 + 8 * istride;

        __syncthreads();

        auto echunk = [&](int tc, float (&ilCur)[4]) __attribute__((always_inline)) {
            #pragma unroll
            for (int dt = 0; dt < 4; ++dt) {
                const int pp = dt & 1;
                const int pn = pp ^ 1;
                const int hr = dt;              // gates' real C/D reg (row 4q+dt)
                const int cr = (dt + 2) & 3;    // cs real C/D reg
                const float il_use = ilCur[dt];

                bf16x8 hcfr[4];
                #pragma unroll
                for (int kt = 0; kt < 4; ++kt)
                    hcfr[kt] = *reinterpret_cast<const bf16x8*>(&hc_a[pp][nl][kt * 32 + q * 8]);
                const int ps = (dt < 3) ? dt : (3 + (tc & 1));
                const f32x4 pav = *reinterpret_cast<const f32x4*>(&pa[ps][q][j][0]);

                ilCur[dt] = ipl[dt * istride];   // reload (chunk +2)

                // recurrent MFMAs; cs chain first (epilogue's serial path starts earliest)
                f32x4 cA = MFMA(hcfr[0], wd_fr[0],     bdv);
                f32x4 g0 = MFMA(hcfr[0], whh_fr[0][0], zc);
                f32x4 g1 = MFMA(hcfr[0], whh_fr[1][0], zc);
                f32x4 g2 = MFMA(hcfr[0], whh_fr[2][0], zc);
                f32x4 g3 = MFMA(hcfr[0], whh_fr[3][0], zc);
                #pragma unroll
                for (int kt = 1; kt < 4; ++kt) {
                    cA = MFMA(hcfr[kt], wd_fr[kt],     cA);
                    g0 = MFMA(hcfr[kt], whh_fr[0][kt], g0);
                    g1 = MFMA(hcfr[kt], whh_fr[1][kt], g1);
                    g2 = MFMA(hcfr[kt], whh_fr[2][kt], g2);
                    g3 = MFMA(hcfr[kt], whh_fr[3][kt], g3);
                }

                // epilogue: x-pre-acts (incl. biases) added in f32 from pa
                {
                    const float cs   = tanh_f(cA[cr]);
                    const float cadj = fmaf(cs, il_use, c_st);
                    const float gf   = sig_f(g1[hr] + pav[1]);
                    const float gi   = sig_f(g0[hr] + pav[0]);
                    const float gg   = tanh_f(g2[hr] + pav[2]);
                    const float cn   = gf * cadj + gi * gg;
                    hc_a[pn][q * 4 + ((dt + 3) & 3)][j] = (__bf16)cn;   // c write early
                    const float go   = sig_f(g3[hr] + pav[3]);
                    const float hn   = go * tanh_f(cn);
                    c_st = cn;
                    hc_a[pn][q * 4 + ((dt + 1) & 3)][j] = (__bf16)hn;
                    *op = hn;
                }
                op += ostride;

                asm volatile("s_waitcnt lgkmcnt(0)\n\ts_barrier" ::: "memory");
            }
            ipl += 4 * istride;
        };

        for (int tc = 0; tc < SEQ / 4; tc += 2) {
            echunk(tc,     ilA);
            echunk(tc + 1, ilB);
        }
    }
}

extern "C" void kernel_launch(void* const* d_in, const int* in_sizes, int n_in,
                              void* d_out, int out_size, void* d_ws, size_t ws_size,
                              hipStream_t stream) {
    const float* x     = (const float*)d_in[0];
    const float* h0    = (const float*)d_in[1];
    const float* c0    = (const float*)d_in[2];
    const float* dts   = (const float*)d_in[3];
    const float* Wih_f = (const float*)d_in[4];
    const float* Whh_f = (const float*)d_in[5];
    const float* bih_f = (const float*)d_in[6];
    const float* bhh_f = (const float*)d_in[7];
    const float* Wd_f  = (const float*)d_in[8];
    const float* bd_f  = (const float*)d_in[9];
    const float* Wih_r = (const float*)d_in[10];
    const float* Whh_r = (const float*)d_in[11];
    const float* bih_r = (const float*)d_in[12];
    const float* bhh_r = (const float*)d_in[13];
    const float* Wd_r  = (const float*)d_in[14];
    const float* bd_r  = (const float*)d_in[15];
    float* out = (float*)d_out;

    __bf16* xbuf = (__bf16*)((char*)d_ws + XB_OFF);
    float*  il   = (float*)((char*)d_ws + IL_OFF);
    __bf16* wb   = (__bf16*)((char*)d_ws + WB_OFF);

    cvt_x_kernel<<<16384, 256, 0, stream>>>(x, xbuf);
    prep_ilog_kernel<<<512, 256, 0, stream>>>(dts, il);
    cvt_w_kernel<<<128, 256, 0, stream>>>(Wih_f, Wih_r, wb);

    tlstm_main<<<32, 768, 0, stream>>>(xbuf, wb, il, h0, c0,
                                       Whh_f, Wd_f, bd_f, bih_f, bhh_f,
                                       Whh_r, Wd_r, bd_r, bih_r, bhh_r,
                                       out);
}